// Round 1
// baseline (1703.502 us; speedup 1.0000x reference)
//
#include <hip/hip_runtime.h>
#include <hip/hip_bf16.h>

// BiPhaseScorer: B=2, S=2048, E=512, H=8, D=64, BETA=0.5, SCALE=8
// scores = beta/D * (cos_q.cos_k + sin_q.sin_k) + (1-beta)/scale * (rq.rk)
// cos(atan2(y,x)) = x/r ; sin = y/r  -> fold into a single 192-dim dot:
//   Qt = [cq*A, sq*A, rq*RB], Kt likewise, A=sqrt(0.5/64), RB=sqrt(0.5/8)=0.25
// V = concat(vxh, vyh) -> 128-dim PV, single softmax serves both channels.

#define N_ROWS 4096   // B*S
#define EDIM 512
#define SEQ 2048
#define NHEAD 8
#define HDIM 64
#define CDIM 192      // 3*HDIM
#define DVDIM 128     // 2*HDIM

#define PHASE_A 0.08838834764831845f   // sqrt(0.5/64)
#define MAG_B   0.25f                  // sqrt(0.5/8)

// ---------------------------------------------------------------------------
// Fused pair GEMM: out0 = X0 @ W0^T + b0 ; out1 = X1 @ W1^T + b1
// MODE 0 (QK): write [B,H,S,192] polar-transformed
// MODE 1 (V) : write [B,H,S,128] interleaved channels
// MODE 2 (OUT): write plain row-major [N,512] to out0/out1
// ---------------------------------------------------------------------------
template <int MODE>
__global__ __launch_bounds__(256) void gemm_pair(
    const float* __restrict__ X0, const float* __restrict__ X1,
    const float* __restrict__ W0, const float* __restrict__ b0,
    const float* __restrict__ W1, const float* __restrict__ b1,
    float* __restrict__ out0, float* __restrict__ out1)
{
    __shared__ float As0[16][64];
    __shared__ float Bs0[16][64];
    __shared__ float As1[16][64];
    __shared__ float Bs1[16][64];

    const int tid = threadIdx.x;
    const int tx = tid & 15, ty = tid >> 4;
    const int m0 = blockIdx.y * 64;
    const int n0 = blockIdx.x * 64;

    const int lrow = tid >> 2;        // 0..63
    const int lk4  = (tid & 3) * 4;   // 0,4,8,12

    float acc0[4][4] = {{0.f}};
    float acc1[4][4] = {{0.f}};

    for (int k0 = 0; k0 < EDIM; k0 += 16) {
        const float4 a0 = *(const float4*)&X0[(size_t)(m0 + lrow) * EDIM + k0 + lk4];
        const float4 a1 = *(const float4*)&X1[(size_t)(m0 + lrow) * EDIM + k0 + lk4];
        const float4 w0 = *(const float4*)&W0[(size_t)(n0 + lrow) * EDIM + k0 + lk4];
        const float4 w1 = *(const float4*)&W1[(size_t)(n0 + lrow) * EDIM + k0 + lk4];
        __syncthreads();   // previous iteration's reads complete
        As0[lk4 + 0][lrow] = a0.x; As0[lk4 + 1][lrow] = a0.y;
        As0[lk4 + 2][lrow] = a0.z; As0[lk4 + 3][lrow] = a0.w;
        As1[lk4 + 0][lrow] = a1.x; As1[lk4 + 1][lrow] = a1.y;
        As1[lk4 + 2][lrow] = a1.z; As1[lk4 + 3][lrow] = a1.w;
        Bs0[lk4 + 0][lrow] = w0.x; Bs0[lk4 + 1][lrow] = w0.y;
        Bs0[lk4 + 2][lrow] = w0.z; Bs0[lk4 + 3][lrow] = w0.w;
        Bs1[lk4 + 0][lrow] = w1.x; Bs1[lk4 + 1][lrow] = w1.y;
        Bs1[lk4 + 2][lrow] = w1.z; Bs1[lk4 + 3][lrow] = w1.w;
        __syncthreads();

        #pragma unroll
        for (int kk = 0; kk < 16; ++kk) {
            float xa0[4], xb0[4], xa1[4], xb1[4];
            *(float4*)xa0 = *(const float4*)&As0[kk][ty * 4];
            *(float4*)xb0 = *(const float4*)&Bs0[kk][tx * 4];
            *(float4*)xa1 = *(const float4*)&As1[kk][ty * 4];
            *(float4*)xb1 = *(const float4*)&Bs1[kk][tx * 4];
            #pragma unroll
            for (int i = 0; i < 4; ++i)
                #pragma unroll
                for (int j = 0; j < 4; ++j) {
                    acc0[i][j] = fmaf(xa0[i], xb0[j], acc0[i][j]);
                    acc1[i][j] = fmaf(xa1[i], xb1[j], acc1[i][j]);
                }
        }
    }

    #pragma unroll
    for (int i = 0; i < 4; ++i) {
        const int m = m0 + ty * 4 + i;
        #pragma unroll
        for (int j = 0; j < 4; ++j) {
            const int n = n0 + tx * 4 + j;
            const float v0 = acc0[i][j] + b0[n];
            const float v1 = acc1[i][j] + b1[n];
            if (MODE == 2) {
                out0[(size_t)m * EDIM + n] = v0;
                out1[(size_t)m * EDIM + n] = v1;
            } else {
                const int b = m >> 11, s = m & (SEQ - 1);
                const int h = n >> 6, d = n & (HDIM - 1);
                if (MODE == 0) {
                    const float r2 = v0 * v0 + v1 * v1;
                    const float r = sqrtf(r2);
                    float c, sn;
                    if (r2 > 0.f) { c = v0 / r; sn = v1 / r; }
                    else          { c = 1.f;    sn = 0.f; }
                    const size_t base =
                        ((size_t)(b * NHEAD + h) * SEQ + s) * CDIM + d;
                    out0[base]       = c  * PHASE_A;
                    out0[base + 64]  = sn * PHASE_A;
                    out0[base + 128] = r  * MAG_B;
                } else { // MODE 1: V
                    const size_t base =
                        ((size_t)(b * NHEAD + h) * SEQ + s) * DVDIM + d;
                    out0[base]      = v0;
                    out0[base + 64] = v1;
                }
            }
        }
    }
}

// ---------------------------------------------------------------------------
// Flash attention: per block one (bh, q-tile of 64). 256 threads (16x16).
// scores 64x64 over 192 dims, online softmax, O[64][128] accumulation.
// Dynamic LDS: Qs[192][64] + Ks[192][64] + Ps[64][64] + Vs[64][128] = 144 KB
// ---------------------------------------------------------------------------
__global__ __launch_bounds__(256) void attn_kernel(
    const float* __restrict__ Qt, const float* __restrict__ Kt,
    const float* __restrict__ Vt,
    float* __restrict__ ax, float* __restrict__ ay)
{
    extern __shared__ float smem[];
    float* Qs = smem;                 // [192][64]
    float* Ks = Qs + CDIM * 64;       // [192][64]
    float* Ps = Ks + CDIM * 64;       // [64][64]
    float* Vs = Ps + 64 * 64;         // [64][128]

    const int tid = threadIdx.x;
    const int tx = tid & 15, ty = tid >> 4;
    const int bh = blockIdx.y;                 // 0..15
    const int q0 = blockIdx.x * 64;
    const int b = bh >> 3, h = bh & 7;

    // Load Q tile transposed: Qs[c][q]
    {
        const float* Qg = Qt + ((size_t)bh * SEQ + q0) * CDIM;
        #pragma unroll
        for (int it = 0; it < 12; ++it) {
            const int idx = it * 256 + tid;        // 0..3071
            const int q = idx / 48;
            const int c4 = (idx % 48) * 4;
            const float4 v = *(const float4*)&Qg[(size_t)q * CDIM + c4];
            Qs[(c4 + 0) * 64 + q] = v.x;
            Qs[(c4 + 1) * 64 + q] = v.y;
            Qs[(c4 + 2) * 64 + q] = v.z;
            Qs[(c4 + 3) * 64 + q] = v.w;
        }
    }

    float m_i[4], l_i[4], acc[4][8];
    #pragma unroll
    for (int i = 0; i < 4; ++i) {
        m_i[i] = -INFINITY; l_i[i] = 0.f;
        #pragma unroll
        for (int j = 0; j < 8; ++j) acc[i][j] = 0.f;
    }

    for (int kt = 0; kt < SEQ / 64; ++kt) {
        __syncthreads();  // previous PV reads done (and Q writes before 1st use)

        // stage K tile transposed, V tile row-major
        {
            const float* Kg = Kt + ((size_t)bh * SEQ + kt * 64) * CDIM;
            #pragma unroll
            for (int it = 0; it < 12; ++it) {
                const int idx = it * 256 + tid;
                const int kr = idx / 48;
                const int c4 = (idx % 48) * 4;
                const float4 v = *(const float4*)&Kg[(size_t)kr * CDIM + c4];
                Ks[(c4 + 0) * 64 + kr] = v.x;
                Ks[(c4 + 1) * 64 + kr] = v.y;
                Ks[(c4 + 2) * 64 + kr] = v.z;
                Ks[(c4 + 3) * 64 + kr] = v.w;
            }
            const float* Vg = Vt + ((size_t)bh * SEQ + kt * 64) * DVDIM;
            #pragma unroll
            for (int it = 0; it < 8; ++it) {
                const int idx = it * 256 + tid;
                const int kr = idx / 32;
                const int c4 = (idx % 32) * 4;
                *(float4*)&Vs[kr * DVDIM + c4] =
                    *(const float4*)&Vg[(size_t)kr * DVDIM + c4];
            }
        }
        __syncthreads();

        // scores s[i][j]: q = ty*4+i, k = tx*4+j
        float s[4][4] = {{0.f}};
        #pragma unroll 4
        for (int c = 0; c < CDIM; ++c) {
            float qv[4], kv[4];
            *(float4*)qv = *(const float4*)&Qs[c * 64 + ty * 4];
            *(float4*)kv = *(const float4*)&Ks[c * 64 + tx * 4];
            #pragma unroll
            for (int i = 0; i < 4; ++i)
                #pragma unroll
                for (int j = 0; j < 4; ++j)
                    s[i][j] = fmaf(qv[i], kv[j], s[i][j]);
        }

        // online softmax per q-row (row spread across the 16 tx lanes)
        #pragma unroll
        for (int i = 0; i < 4; ++i) {
            float mt = fmaxf(fmaxf(s[i][0], s[i][1]), fmaxf(s[i][2], s[i][3]));
            mt = fmaxf(mt, __shfl_xor(mt, 1));
            mt = fmaxf(mt, __shfl_xor(mt, 2));
            mt = fmaxf(mt, __shfl_xor(mt, 4));
            mt = fmaxf(mt, __shfl_xor(mt, 8));
            const float mnew = fmaxf(m_i[i], mt);
            const float scale = expf(m_i[i] - mnew);
            float rs = 0.f;
            #pragma unroll
            for (int j = 0; j < 4; ++j) {
                s[i][j] = expf(s[i][j] - mnew);
                rs += s[i][j];
            }
            rs += __shfl_xor(rs, 1);
            rs += __shfl_xor(rs, 2);
            rs += __shfl_xor(rs, 4);
            rs += __shfl_xor(rs, 8);
            l_i[i] = l_i[i] * scale + rs;
            m_i[i] = mnew;
            #pragma unroll
            for (int j = 0; j < 8; ++j) acc[i][j] *= scale;
            float4 pv;
            pv.x = s[i][0]; pv.y = s[i][1]; pv.z = s[i][2]; pv.w = s[i][3];
            *(float4*)&Ps[(ty * 4 + i) * 64 + tx * 4] = pv;
        }
        __syncthreads();

        // PV: O[q][v] += P[q][k] * V[k][v];  q = ty*4+i, v = tx*8+j
        #pragma unroll 2
        for (int kk4 = 0; kk4 < 16; ++kk4) {
            float p[4][4];
            #pragma unroll
            for (int i = 0; i < 4; ++i)
                *(float4*)p[i] = *(const float4*)&Ps[(ty * 4 + i) * 64 + kk4 * 4];
            #pragma unroll
            for (int t = 0; t < 4; ++t) {
                float v0[4], v1[4];
                *(float4*)v0 = *(const float4*)&Vs[(kk4 * 4 + t) * DVDIM + tx * 8];
                *(float4*)v1 = *(const float4*)&Vs[(kk4 * 4 + t) * DVDIM + tx * 8 + 4];
                #pragma unroll
                for (int i = 0; i < 4; ++i) {
                    #pragma unroll
                    for (int j = 0; j < 4; ++j) {
                        acc[i][j]     = fmaf(p[i][t], v0[j], acc[i][j]);
                        acc[i][j + 4] = fmaf(p[i][t], v1[j], acc[i][j + 4]);
                    }
                }
            }
        }
    }

    // epilogue: divide by l, write merged [B,S,E] layout
    #pragma unroll
    for (int i = 0; i < 4; ++i) {
        const float inv = 1.f / l_i[i];
        const int qrow = q0 + ty * 4 + i;
        const size_t ofs = ((size_t)(b * SEQ + qrow)) * EDIM + h * HDIM;
        float out8[8];
        #pragma unroll
        for (int j = 0; j < 8; ++j) out8[j] = acc[i][j] * inv;
        float* outp = (tx < 8) ? (ax + ofs + tx * 8) : (ay + ofs + tx * 8 - 64);
        *(float4*)&outp[0] = *(float4*)&out8[0];
        *(float4*)&outp[4] = *(float4*)&out8[4];
    }
}

// ---------------------------------------------------------------------------
extern "C" void kernel_launch(void* const* d_in, const int* in_sizes, int n_in,
                              void* d_out, int out_size, void* d_ws, size_t ws_size,
                              hipStream_t stream)
{
    const float* qx  = (const float*)d_in[0];
    const float* qy  = (const float*)d_in[1];
    const float* kx  = (const float*)d_in[2];
    const float* ky  = (const float*)d_in[3];
    const float* vx  = (const float*)d_in[4];
    const float* vy  = (const float*)d_in[5];
    const float* Wqx = (const float*)d_in[6];  const float* bqx = (const float*)d_in[7];
    const float* Wqy = (const float*)d_in[8];  const float* bqy = (const float*)d_in[9];
    const float* Wkx = (const float*)d_in[10]; const float* bkx = (const float*)d_in[11];
    const float* Wky = (const float*)d_in[12]; const float* bky = (const float*)d_in[13];
    const float* Wvx = (const float*)d_in[14]; const float* bvx = (const float*)d_in[15];
    const float* Wvy = (const float*)d_in[16]; const float* bvy = (const float*)d_in[17];
    const float* Wox = (const float*)d_in[18]; const float* box = (const float*)d_in[19];
    const float* Woy = (const float*)d_in[20]; const float* boy = (const float*)d_in[21];

    float* outx = (float*)d_out;              // [2,2048,512]
    float* outy = outx + 2097152;

    float* ws = (float*)d_ws;
    float* Qt = ws;                           // [B,H,S,192] = 6291456
    float* Kt = Qt + 6291456;                 // 6291456
    float* Vt = Kt + 6291456;                 // [B,H,S,128] = 4194304
    float* ax = Vt + 4194304;                 // [B,S,E] = 2097152
    float* ay = ax + 2097152;                 // 2097152
    // total ws use: 20971520 floats = 83.9 MB

    const dim3 blk(256);
    const dim3 gproj(EDIM / 64, N_ROWS / 64);  // (8, 64)

    hipLaunchKernelGGL((gemm_pair<0>), gproj, blk, 0, stream,
                       qx, qy, Wqx, bqx, Wqy, bqy, Qt, nullptr);
    hipLaunchKernelGGL((gemm_pair<0>), gproj, blk, 0, stream,
                       kx, ky, Wkx, bkx, Wky, bky, Kt, nullptr);
    hipLaunchKernelGGL((gemm_pair<1>), gproj, blk, 0, stream,
                       vx, vy, Wvx, bvx, Wvy, bvy, Vt, nullptr);

    const int lds_bytes = (CDIM * 64 + CDIM * 64 + 64 * 64 + 64 * DVDIM) * 4; // 147456
    hipFuncSetAttribute((const void*)attn_kernel,
                        hipFuncAttributeMaxDynamicSharedMemorySize, lds_bytes);
    hipLaunchKernelGGL(attn_kernel, dim3(SEQ / 64, 16), blk, lds_bytes, stream,
                       Qt, Kt, Vt, ax, ay);

    hipLaunchKernelGGL((gemm_pair<2>), gproj, blk, 0, stream,
                       ax, ay, Wox, box, Woy, boy, outx, outy);
}

// Round 2
// 432.709 us; speedup vs baseline: 3.9368x; 3.9368x over previous
//
#include <hip/hip_runtime.h>
#include <hip/hip_bf16.h>

// BiPhaseScorer: B=2, S=2048, E=512, H=8, D=64, BETA=0.5, SCALE=8
// scores = beta/D * (cos.cos + sin.sin) + (1-beta)/scale * (rq.rk)
// folded to one 192-dim dot: Qt = [cq*A, sq*A, rq*RB], A=sqrt(0.5/64), RB=0.25
// V = concat(vxh, vyh) -> 128-dim PV, one softmax serves both channels.
// Attention path in fp16 MFMA (16x16x32), accumulate fp32.

#define N_ROWS 4096   // B*S
#define EDIM 512
#define SEQ 2048
#define NHEAD 8
#define HDIM 64
#define CDIM 192      // 3*HDIM
#define DV 128        // 2*HDIM

#define PHASE_A 0.08838834764831845f   // sqrt(0.5/64)
#define MAG_B   0.25f                  // sqrt(0.5/8)

typedef _Float16 half8 __attribute__((ext_vector_type(8)));
typedef float f32x4 __attribute__((ext_vector_type(4)));

// ---------------------------------------------------------------------------
// Fused pair GEMM (fp32 compute): out0 = X0 @ W0^T + b0 ; out1 = X1 @ W1^T + b1
// MODE 0 (QK): write fp16 [bh][s][192] polar-transformed
// MODE 1 (V) : write fp16 V^T [bh][dv=128][S]  (dv = d for x, 64+d for y)
// MODE 2 (OUT): write plain fp32 row-major [N,512] to out0/out1
// ---------------------------------------------------------------------------
template <int MODE>
__global__ __launch_bounds__(256) void gemm_pair(
    const float* __restrict__ X0, const float* __restrict__ X1,
    const float* __restrict__ W0, const float* __restrict__ b0,
    const float* __restrict__ W1, const float* __restrict__ b1,
    void* __restrict__ out0, void* __restrict__ out1)
{
    __shared__ float As0[16][64];
    __shared__ float Bs0[16][64];
    __shared__ float As1[16][64];
    __shared__ float Bs1[16][64];

    const int tid = threadIdx.x;
    const int tx = tid & 15, ty = tid >> 4;
    const int m0 = blockIdx.y * 64;
    const int n0 = blockIdx.x * 64;

    const int lrow = tid >> 2;        // 0..63
    const int lk4  = (tid & 3) * 4;   // 0,4,8,12

    float acc0[4][4] = {{0.f}};
    float acc1[4][4] = {{0.f}};

    for (int k0 = 0; k0 < EDIM; k0 += 16) {
        const float4 a0 = *(const float4*)&X0[(size_t)(m0 + lrow) * EDIM + k0 + lk4];
        const float4 a1 = *(const float4*)&X1[(size_t)(m0 + lrow) * EDIM + k0 + lk4];
        const float4 w0 = *(const float4*)&W0[(size_t)(n0 + lrow) * EDIM + k0 + lk4];
        const float4 w1 = *(const float4*)&W1[(size_t)(n0 + lrow) * EDIM + k0 + lk4];
        __syncthreads();
        As0[lk4 + 0][lrow] = a0.x; As0[lk4 + 1][lrow] = a0.y;
        As0[lk4 + 2][lrow] = a0.z; As0[lk4 + 3][lrow] = a0.w;
        As1[lk4 + 0][lrow] = a1.x; As1[lk4 + 1][lrow] = a1.y;
        As1[lk4 + 2][lrow] = a1.z; As1[lk4 + 3][lrow] = a1.w;
        Bs0[lk4 + 0][lrow] = w0.x; Bs0[lk4 + 1][lrow] = w0.y;
        Bs0[lk4 + 2][lrow] = w0.z; Bs0[lk4 + 3][lrow] = w0.w;
        Bs1[lk4 + 0][lrow] = w1.x; Bs1[lk4 + 1][lrow] = w1.y;
        Bs1[lk4 + 2][lrow] = w1.z; Bs1[lk4 + 3][lrow] = w1.w;
        __syncthreads();

        #pragma unroll
        for (int kk = 0; kk < 16; ++kk) {
            float xa0[4], xb0[4], xa1[4], xb1[4];
            *(float4*)xa0 = *(const float4*)&As0[kk][ty * 4];
            *(float4*)xb0 = *(const float4*)&Bs0[kk][tx * 4];
            *(float4*)xa1 = *(const float4*)&As1[kk][ty * 4];
            *(float4*)xb1 = *(const float4*)&Bs1[kk][tx * 4];
            #pragma unroll
            for (int i = 0; i < 4; ++i)
                #pragma unroll
                for (int j = 0; j < 4; ++j) {
                    acc0[i][j] = fmaf(xa0[i], xb0[j], acc0[i][j]);
                    acc1[i][j] = fmaf(xa1[i], xb1[j], acc1[i][j]);
                }
        }
    }

    #pragma unroll
    for (int i = 0; i < 4; ++i) {
        const int m = m0 + ty * 4 + i;
        #pragma unroll
        for (int j = 0; j < 4; ++j) {
            const int n = n0 + tx * 4 + j;
            const float v0 = acc0[i][j] + b0[n];
            const float v1 = acc1[i][j] + b1[n];
            if (MODE == 2) {
                ((float*)out0)[(size_t)m * EDIM + n] = v0;
                ((float*)out1)[(size_t)m * EDIM + n] = v1;
            } else {
                const int b = m >> 11, s = m & (SEQ - 1);
                const int h = n >> 6, d = n & (HDIM - 1);
                const int bh = b * NHEAD + h;
                if (MODE == 0) {
                    const float r2 = v0 * v0 + v1 * v1;
                    const float r = sqrtf(r2);
                    float c, sn;
                    if (r2 > 0.f) { c = v0 / r; sn = v1 / r; }
                    else          { c = 1.f;    sn = 0.f; }
                    _Float16* o = (_Float16*)out0;
                    const size_t base = ((size_t)bh * SEQ + s) * CDIM + d;
                    o[base]       = (_Float16)(c  * PHASE_A);
                    o[base + 64]  = (_Float16)(sn * PHASE_A);
                    o[base + 128] = (_Float16)(r  * MAG_B);
                } else { // MODE 1: V^T fp16 [bh][dv][S]
                    _Float16* o = (_Float16*)out0;
                    o[((size_t)bh * DV + d)      * SEQ + s] = (_Float16)v0;
                    o[((size_t)bh * DV + 64 + d) * SEQ + s] = (_Float16)v1;
                }
            }
        }
    }
}

// ---------------------------------------------------------------------------
// fp16 MFMA flash attention.
// Block: 512 threads = 8 waves; each wave owns 16 q-rows (BQ=128). BK=64.
// Scores computed TRANSPOSED: st = mfma(A=K_tile, B=Q^T) -> D[k-row][q-col],
// so softmax k-reduce = 16 in-lane values + shfl_xor(16,32).
// P packed to per-wave LDS (4 consecutive k per store), re-read as PV A-op.
// K LDS [64][192], V^T LDS [128][64], P LDS [8][16][64]; all XOR-swizzled
// (byte ^= (row&7)<<4) -> optimal 8-phase b128 accesses.
// ---------------------------------------------------------------------------
__global__ __launch_bounds__(512, 2) void attn_mfma(
    const _Float16* __restrict__ Qg, const _Float16* __restrict__ Kg,
    const _Float16* __restrict__ Vg,
    float* __restrict__ ax, float* __restrict__ ay)
{
    __shared__ char KsB[64 * 384];      // 24 KB
    __shared__ char VsB[128 * 128];     // 16 KB (V^T)
    __shared__ char PsB[8 * 16 * 128];  // 16 KB (per-wave P)

    const int tid = threadIdx.x;
    const int w  = tid >> 6;
    const int l  = tid & 63;
    const int g  = l >> 4;      // 0..3
    const int ql = l & 15;
    const int bh = blockIdx.y;
    const int b  = bh >> 3, h = bh & 7;
    const int q0 = blockIdx.x * 128;
    const int qrow = q0 + w * 16 + ql;

    // Q B-fragments in registers: B[c][q-col] = Q[qrow][c], 8 contiguous c/lane
    half8 qf[6];
    {
        const char* qp = (const char*)(Qg + ((size_t)bh * SEQ + qrow) * CDIM);
        #pragma unroll
        for (int c = 0; c < 6; ++c) {
            uint4 u = *(const uint4*)(qp + c * 64 + g * 16);
            qf[c] = __builtin_bit_cast(half8, u);
        }
    }

    f32x4 o[8];
    #pragma unroll
    for (int vt = 0; vt < 8; ++vt) o[vt] = (f32x4){0.f, 0.f, 0.f, 0.f};
    float m_i = -INFINITY, l_i = 0.f;

    const char* kgb = (const char*)(Kg + (size_t)bh * SEQ * CDIM);
    const char* vgb = (const char*)(Vg + (size_t)bh * DV * SEQ);

    for (int kt0 = 0; kt0 < SEQ; kt0 += 64) {
        __syncthreads();
        // stage K tile: 64 rows x 384 B = 1536 x 16B chunks
        #pragma unroll
        for (int i = 0; i < 3; ++i) {
            const int id = i * 512 + tid;
            const int r = id / 24, cb = (id % 24) * 16;
            uint4 u = *(const uint4*)(kgb + (size_t)(kt0 + r) * 384 + cb);
            *(uint4*)(KsB + ((r * 384 + cb) ^ ((r & 7) << 4))) = u;
        }
        // stage V^T tile: 128 rows x 128 B = 1024 chunks
        #pragma unroll
        for (int i = 0; i < 2; ++i) {
            const int id = i * 512 + tid;
            const int r = id / 8, cb = (id % 8) * 16;
            uint4 u = *(const uint4*)(vgb + (size_t)r * 4096 + kt0 * 2 + cb);
            *(uint4*)(VsB + ((r * 128 + cb) ^ ((r & 7) << 4))) = u;
        }
        __syncthreads();

        // S^T tiles: st[kt][reg] = S[q = ql][k = kt*16 + g*4 + reg]
        f32x4 st[4];
        #pragma unroll
        for (int kt = 0; kt < 4; ++kt) {
            f32x4 acc = {0.f, 0.f, 0.f, 0.f};
            const int r = kt * 16 + ql;
            #pragma unroll
            for (int c = 0; c < 6; ++c) {
                uint4 u = *(const uint4*)(
                    KsB + ((r * 384 + c * 64 + g * 16) ^ ((r & 7) << 4)));
                acc = __builtin_amdgcn_mfma_f32_16x16x32_f16(
                    __builtin_bit_cast(half8, u), qf[c], acc, 0, 0, 0);
            }
            st[kt] = acc;
        }

        // online softmax for q = ql (16 in-lane + butterfly over groups)
        float mt = -INFINITY;
        #pragma unroll
        for (int kt = 0; kt < 4; ++kt)
            #pragma unroll
            for (int r = 0; r < 4; ++r) mt = fmaxf(mt, st[kt][r]);
        mt = fmaxf(mt, __shfl_xor(mt, 16));
        mt = fmaxf(mt, __shfl_xor(mt, 32));
        const float mnew = fmaxf(m_i, mt);
        const float sc = __expf(m_i - mnew);
        float rs = 0.f;
        #pragma unroll
        for (int kt = 0; kt < 4; ++kt)
            #pragma unroll
            for (int r = 0; r < 4; ++r) {
                const float p = __expf(st[kt][r] - mnew);
                st[kt][r] = p; rs += p;
            }
        rs += __shfl_xor(rs, 16);
        rs += __shfl_xor(rs, 32);
        l_i = l_i * sc + rs;
        m_i = mnew;

        // write P to per-wave LDS: Ps[w][q=ql][k], 4 consecutive k per store
        #pragma unroll
        for (int kt = 0; kt < 4; ++kt) {
            union { _Float16 hh[4]; uint2 u; } pk;
            pk.hh[0] = (_Float16)st[kt][0]; pk.hh[1] = (_Float16)st[kt][1];
            pk.hh[2] = (_Float16)st[kt][2]; pk.hh[3] = (_Float16)st[kt][3];
            const int byte = w * 2048 + ql * 128 + kt * 32 + g * 8;
            *(uint2*)(PsB + (byte ^ ((ql & 7) << 4))) = pk.u;
        }

        // rescale O: factor per D-row (q-local = g*4+reg) via shuffle
        const float f0 = __shfl(sc, g * 4 + 0);
        const float f1 = __shfl(sc, g * 4 + 1);
        const float f2 = __shfl(sc, g * 4 + 2);
        const float f3 = __shfl(sc, g * 4 + 3);
        #pragma unroll
        for (int vt = 0; vt < 8; ++vt) {
            o[vt][0] *= f0; o[vt][1] *= f1; o[vt][2] *= f2; o[vt][3] *= f3;
        }

        // PV: A = P rows (q x k), B = V (k x v) from V^T LDS
        half8 pf[2];
        #pragma unroll
        for (int ks = 0; ks < 2; ++ks) {
            const int byte = w * 2048 + ql * 128 + ks * 64 + g * 16;
            uint4 u = *(const uint4*)(PsB + (byte ^ ((ql & 7) << 4)));
            pf[ks] = __builtin_bit_cast(half8, u);
        }
        #pragma unroll
        for (int vt = 0; vt < 8; ++vt) {
            const int v = vt * 16 + ql;
            uint4 u0 = *(const uint4*)(
                VsB + ((v * 128 + g * 16) ^ ((v & 7) << 4)));
            uint4 u1 = *(const uint4*)(
                VsB + ((v * 128 + 64 + g * 16) ^ ((v & 7) << 4)));
            o[vt] = __builtin_amdgcn_mfma_f32_16x16x32_f16(
                pf[0], __builtin_bit_cast(half8, u0), o[vt], 0, 0, 0);
            o[vt] = __builtin_amdgcn_mfma_f32_16x16x32_f16(
                pf[1], __builtin_bit_cast(half8, u1), o[vt], 0, 0, 0);
        }
    }

    // epilogue: divide by l (per D-row via shuffle), write fp32 [B,S,E]
    const float invl = 1.f / l_i;
    const float fi0 = __shfl(invl, g * 4 + 0);
    const float fi1 = __shfl(invl, g * 4 + 1);
    const float fi2 = __shfl(invl, g * 4 + 2);
    const float fi3 = __shfl(invl, g * 4 + 3);
    #pragma unroll
    for (int vt = 0; vt < 8; ++vt) {
        const int v = vt * 16 + ql;
        float* basep = (vt < 4) ? ax : ay;
        const int vv = v & 63;
        const float fi[4] = {fi0, fi1, fi2, fi3};
        #pragma unroll
        for (int r = 0; r < 4; ++r) {
            const int q = q0 + w * 16 + g * 4 + r;
            basep[((size_t)(b * SEQ + q)) * EDIM + h * HDIM + vv] = o[vt][r] * fi[r];
        }
    }
}

// ---------------------------------------------------------------------------
extern "C" void kernel_launch(void* const* d_in, const int* in_sizes, int n_in,
                              void* d_out, int out_size, void* d_ws, size_t ws_size,
                              hipStream_t stream)
{
    const float* qx  = (const float*)d_in[0];
    const float* qy  = (const float*)d_in[1];
    const float* kx  = (const float*)d_in[2];
    const float* ky  = (const float*)d_in[3];
    const float* vx  = (const float*)d_in[4];
    const float* vy  = (const float*)d_in[5];
    const float* Wqx = (const float*)d_in[6];  const float* bqx = (const float*)d_in[7];
    const float* Wqy = (const float*)d_in[8];  const float* bqy = (const float*)d_in[9];
    const float* Wkx = (const float*)d_in[10]; const float* bkx = (const float*)d_in[11];
    const float* Wky = (const float*)d_in[12]; const float* bky = (const float*)d_in[13];
    const float* Wvx = (const float*)d_in[14]; const float* bvx = (const float*)d_in[15];
    const float* Wvy = (const float*)d_in[16]; const float* bvy = (const float*)d_in[17];
    const float* Wox = (const float*)d_in[18]; const float* box = (const float*)d_in[19];
    const float* Woy = (const float*)d_in[20]; const float* boy = (const float*)d_in[21];

    float* outx = (float*)d_out;              // [2,2048,512]
    float* outy = outx + 2097152;

    _Float16* Qt16 = (_Float16*)d_ws;         // [16][2048][192] = 6291456
    _Float16* Kt16 = Qt16 + 6291456;          // 6291456
    _Float16* Vt16 = Kt16 + 6291456;          // [16][128][2048] = 4194304
    float* axp = (float*)(Vt16 + 4194304);    // [B,S,E] fp32
    float* ayp = axp + 2097152;
    // ws bytes: 2*12.6MB + 8.4MB + 2*8.4MB = 48 MB

    const dim3 blk(256);
    const dim3 gproj(EDIM / 64, N_ROWS / 64);  // (8, 64)

    hipLaunchKernelGGL((gemm_pair<0>), gproj, blk, 0, stream,
                       qx, qy, Wqx, bqx, Wqy, bqy, (void*)Qt16, nullptr);
    hipLaunchKernelGGL((gemm_pair<0>), gproj, blk, 0, stream,
                       kx, ky, Wkx, bkx, Wky, bky, (void*)Kt16, nullptr);
    hipLaunchKernelGGL((gemm_pair<1>), gproj, blk, 0, stream,
                       vx, vy, Wvx, bvx, Wvy, bvy, (void*)Vt16, nullptr);

    hipLaunchKernelGGL(attn_mfma, dim3(SEQ / 128, 16), dim3(512), 0, stream,
                       Qt16, Kt16, Vt16, axp, ayp);

    hipLaunchKernelGGL((gemm_pair<2>), gproj, blk, 0, stream,
                       axp, ayp, Wox, box, Woy, boy, (void*)outx, (void*)outy);
}

// Round 3
// 183.958 us; speedup vs baseline: 9.2603x; 2.3522x over previous
//
#include <hip/hip_runtime.h>
#include <hip/hip_bf16.h>

// BiPhaseScorer: B=2, S=2048, E=512, H=8, D=64, BETA=0.5, SCALE=8
// scores folded to one 192-dim dot: Qt = [cq*A, sq*A, rq*RB]
// A=sqrt(0.5/64), RB=0.25; V = concat(vxh,vyh) -> 128-dim PV, one softmax.
// Round 3: all projections on fp16 MFMA (fp32 accum) via cvt pass +
// global_load_lds staging; attn unchanged but emits fp16 ax/ay.

#define N_ROWS 4096   // B*S
#define EDIM 512
#define SEQ 2048
#define NHEAD 8
#define HDIM 64
#define CDIM 192      // 3*HDIM
#define DV 128        // 2*HDIM

#define PHASE_A 0.08838834764831845f   // sqrt(0.5/64)
#define MAG_B   0.25f                  // sqrt(0.5/8)

typedef _Float16 half8 __attribute__((ext_vector_type(8)));
typedef float f32x4 __attribute__((ext_vector_type(4)));

__device__ inline void gload16(const void* g, void* l) {
    __builtin_amdgcn_global_load_lds(
        (const __attribute__((address_space(1))) unsigned int*)g,
        (__attribute__((address_space(3))) unsigned int*)l, 16, 0, 0);
}

// ---------------------------------------------------------------------------
// fp32 -> fp16 conversion, 8 elems/thread
// ---------------------------------------------------------------------------
struct Cvt8 { const float* s[8]; _Float16* d[8]; };

__global__ __launch_bounds__(256) void cvt_fp16(Cvt8 j, int n8) {
    const float* s = j.s[blockIdx.y];
    _Float16* d = j.d[blockIdx.y];
    union U { _Float16 h[8]; uint4 u; };
    for (int i = blockIdx.x * 256 + threadIdx.x; i < n8; i += gridDim.x * 256) {
        const float4 f0 = ((const float4*)s)[2 * i];
        const float4 f1 = ((const float4*)s)[2 * i + 1];
        U u;
        u.h[0] = (_Float16)f0.x; u.h[1] = (_Float16)f0.y;
        u.h[2] = (_Float16)f0.z; u.h[3] = (_Float16)f0.w;
        u.h[4] = (_Float16)f1.x; u.h[5] = (_Float16)f1.y;
        u.h[6] = (_Float16)f1.z; u.h[7] = (_Float16)f1.w;
        ((uint4*)d)[i] = u.u;
    }
}

// ---------------------------------------------------------------------------
// fp16 MFMA pair GEMM: out0 = X0 @ W0^T + b0 ; out1 = X1 @ W1^T + b1
// Tile BM=128 x BN=64 x BK=32, 256 thr = 4 waves (2x2), 16x16x32 MFMA.
// FUSED=1: grid.z in {0,1,2} selects {Q,K,V} arg set + epilogue
//   z<2 : polar transform -> fp16 [bh][s][192]
//   z==2: V^T fp16 [bh][dv][S], packed 8B stores
// FUSED=0: plain fp32 row-major [N,512] outputs (out-projection)
// LDS chunk swizzle: c_phys = c ^ ((row>>1)&3); staged with pre-swizzled
// global source (linear LDS dest, rule 21), read back with same XOR.
// ---------------------------------------------------------------------------
struct PairArgs {
    const _Float16* x0; const _Float16* x1;
    const _Float16* w0; const _Float16* w1;
    const float* b0;    const float* b1;
    void* dst0;         void* dst1;
};

template <int FUSED>
__global__ __launch_bounds__(256, 3) void gemm16(PairArgs A0, PairArgs A1, PairArgs A2)
{
    __shared__ _Float16 As0[128 * 32];
    __shared__ _Float16 As1[128 * 32];
    __shared__ _Float16 Bs0[64 * 32];
    __shared__ _Float16 Bs1[64 * 32];

    const int tid = threadIdx.x;
    const int w = tid >> 6, l = tid & 63;
    const int g = l >> 4, ql = l & 15;
    const int wr = w >> 1, wc = w & 1;
    const int z = FUSED ? blockIdx.z : 0;
    const PairArgs& A = FUSED ? (z == 0 ? A0 : (z == 1 ? A1 : A2)) : A0;

    const int m0 = blockIdx.y * 128;
    const int n0 = blockIdx.x * 64;

    f32x4 acc0[4][2], acc1[4][2];
    #pragma unroll
    for (int f = 0; f < 4; ++f)
        #pragma unroll
        for (int e = 0; e < 2; ++e) {
            acc0[f][e] = (f32x4){0.f, 0.f, 0.f, 0.f};
            acc1[f][e] = (f32x4){0.f, 0.f, 0.f, 0.f};
        }

    for (int k0 = 0; k0 < EDIM; k0 += 32) {
        __syncthreads();
        // ---- stage via global_load_lds (linear dest, pre-swizzled source)
        #pragma unroll
        for (int i = 0; i < 2; ++i) {          // As0: slots 0..511
            const int s = i * 256 + tid;
            const int row = s >> 2, c = s & 3;
            const int cs = c ^ ((row >> 1) & 3);
            gload16(A.x0 + (size_t)(m0 + row) * EDIM + k0 + cs * 8,
                    As0 + (i * 256 + w * 64) * 8);
        }
        #pragma unroll
        for (int i = 0; i < 2; ++i) {          // As1
            const int s = i * 256 + tid;
            const int row = s >> 2, c = s & 3;
            const int cs = c ^ ((row >> 1) & 3);
            gload16(A.x1 + (size_t)(m0 + row) * EDIM + k0 + cs * 8,
                    As1 + (i * 256 + w * 64) * 8);
        }
        {                                      // Bs0: slots 0..255
            const int row = tid >> 2, c = tid & 3;
            const int cs = c ^ ((row >> 1) & 3);
            gload16(A.w0 + (size_t)(n0 + row) * EDIM + k0 + cs * 8,
                    Bs0 + (w * 64) * 8);
            gload16(A.w1 + (size_t)(n0 + row) * EDIM + k0 + cs * 8,
                    Bs1 + (w * 64) * 8);
        }
        __syncthreads();

        // ---- fragments + MFMA
        half8 af0[4], af1[4], bf0[2], bf1[2];
        #pragma unroll
        for (int f = 0; f < 4; ++f) {
            const int arow = wr * 64 + f * 16 + ql;
            const int byo = arow * 64 + ((g ^ ((arow >> 1) & 3)) << 4);
            af0[f] = *(const half8*)((const char*)As0 + byo);
            af1[f] = *(const half8*)((const char*)As1 + byo);
        }
        #pragma unroll
        for (int e = 0; e < 2; ++e) {
            const int brow = wc * 32 + e * 16 + ql;
            const int byo = brow * 64 + ((g ^ ((brow >> 1) & 3)) << 4);
            bf0[e] = *(const half8*)((const char*)Bs0 + byo);
            bf1[e] = *(const half8*)((const char*)Bs1 + byo);
        }
        #pragma unroll
        for (int f = 0; f < 4; ++f)
            #pragma unroll
            for (int e = 0; e < 2; ++e) {
                acc0[f][e] = __builtin_amdgcn_mfma_f32_16x16x32_f16(
                    af0[f], bf0[e], acc0[f][e], 0, 0, 0);
                acc1[f][e] = __builtin_amdgcn_mfma_f32_16x16x32_f16(
                    af1[f], bf1[e], acc1[f][e], 0, 0, 0);
            }
    }

    // ---- epilogue
    #pragma unroll
    for (int f = 0; f < 4; ++f) {
        const int mb = m0 + wr * 64 + f * 16 + g * 4;   // 4 consecutive rows
        #pragma unroll
        for (int e = 0; e < 2; ++e) {
            const int n = n0 + wc * 32 + e * 16 + ql;
            const float bias0 = A.b0[n];
            const float bias1 = A.b1[n];
            if (!FUSED) {
                float* o0 = (float*)A.dst0;
                float* o1 = (float*)A.dst1;
                #pragma unroll
                for (int r = 0; r < 4; ++r) {
                    const int m = mb + r;
                    o0[(size_t)m * EDIM + n] = acc0[f][e][r] + bias0;
                    o1[(size_t)m * EDIM + n] = acc1[f][e][r] + bias1;
                }
            } else {
                const int b = mb >> 11, s = mb & (SEQ - 1);
                const int h = blockIdx.x;          // n >> 6 (BN=64)
                const int d = n & (HDIM - 1);
                const int bh = b * NHEAD + h;
                _Float16* dst = (_Float16*)A.dst0;
                if (z != 2) {   // polar -> Qt/Kt [bh][s][192]
                    const size_t base = ((size_t)bh * SEQ + s) * CDIM + d;
                    #pragma unroll
                    for (int r = 0; r < 4; ++r) {
                        const float v0 = acc0[f][e][r] + bias0;
                        const float v1 = acc1[f][e][r] + bias1;
                        const float r2 = v0 * v0 + v1 * v1;
                        const float rm = sqrtf(r2);
                        float c, sn;
                        if (r2 > 0.f) { c = v0 / rm; sn = v1 / rm; }
                        else          { c = 1.f;     sn = 0.f; }
                        dst[base + (size_t)r * CDIM]       = (_Float16)(c  * PHASE_A);
                        dst[base + (size_t)r * CDIM + 64]  = (_Float16)(sn * PHASE_A);
                        dst[base + (size_t)r * CDIM + 128] = (_Float16)(rm * MAG_B);
                    }
                } else {        // V^T [bh][dv][S], pack 4 consecutive s
                    union Pk { _Float16 h[4]; uint2 u; } p0, p1;
                    #pragma unroll
                    for (int r = 0; r < 4; ++r) {
                        p0.h[r] = (_Float16)(acc0[f][e][r] + bias0);
                        p1.h[r] = (_Float16)(acc1[f][e][r] + bias1);
                    }
                    *(uint2*)&dst[((size_t)bh * DV + d) * SEQ + s]      = p0.u;
                    *(uint2*)&dst[((size_t)bh * DV + 64 + d) * SEQ + s] = p1.u;
                }
            }
        }
    }
}

// ---------------------------------------------------------------------------
// fp16 MFMA flash attention (unchanged from round 2 except fp16 ax/ay out).
// ---------------------------------------------------------------------------
__global__ __launch_bounds__(512, 2) void attn_mfma(
    const _Float16* __restrict__ Qg, const _Float16* __restrict__ Kg,
    const _Float16* __restrict__ Vg,
    _Float16* __restrict__ ax, _Float16* __restrict__ ay)
{
    __shared__ char KsB[64 * 384];      // 24 KB
    __shared__ char VsB[128 * 128];     // 16 KB (V^T)
    __shared__ char PsB[8 * 16 * 128];  // 16 KB (per-wave P)

    const int tid = threadIdx.x;
    const int w  = tid >> 6;
    const int l  = tid & 63;
    const int g  = l >> 4;
    const int ql = l & 15;
    const int bh = blockIdx.y;
    const int b  = bh >> 3, h = bh & 7;
    const int q0 = blockIdx.x * 128;
    const int qrow = q0 + w * 16 + ql;

    half8 qf[6];
    {
        const char* qp = (const char*)(Qg + ((size_t)bh * SEQ + qrow) * CDIM);
        #pragma unroll
        for (int c = 0; c < 6; ++c) {
            uint4 u = *(const uint4*)(qp + c * 64 + g * 16);
            qf[c] = __builtin_bit_cast(half8, u);
        }
    }

    f32x4 o[8];
    #pragma unroll
    for (int vt = 0; vt < 8; ++vt) o[vt] = (f32x4){0.f, 0.f, 0.f, 0.f};
    float m_i = -INFINITY, l_i = 0.f;

    const char* kgb = (const char*)(Kg + (size_t)bh * SEQ * CDIM);
    const char* vgb = (const char*)(Vg + (size_t)bh * DV * SEQ);

    for (int kt0 = 0; kt0 < SEQ; kt0 += 64) {
        __syncthreads();
        #pragma unroll
        for (int i = 0; i < 3; ++i) {
            const int id = i * 512 + tid;
            const int r = id / 24, cb = (id % 24) * 16;
            uint4 u = *(const uint4*)(kgb + (size_t)(kt0 + r) * 384 + cb);
            *(uint4*)(KsB + ((r * 384 + cb) ^ ((r & 7) << 4))) = u;
        }
        #pragma unroll
        for (int i = 0; i < 2; ++i) {
            const int id = i * 512 + tid;
            const int r = id / 8, cb = (id % 8) * 16;
            uint4 u = *(const uint4*)(vgb + (size_t)r * 4096 + kt0 * 2 + cb);
            *(uint4*)(VsB + ((r * 128 + cb) ^ ((r & 7) << 4))) = u;
        }
        __syncthreads();

        f32x4 st[4];
        #pragma unroll
        for (int kt = 0; kt < 4; ++kt) {
            f32x4 acc = {0.f, 0.f, 0.f, 0.f};
            const int r = kt * 16 + ql;
            #pragma unroll
            for (int c = 0; c < 6; ++c) {
                uint4 u = *(const uint4*)(
                    KsB + ((r * 384 + c * 64 + g * 16) ^ ((r & 7) << 4)));
                acc = __builtin_amdgcn_mfma_f32_16x16x32_f16(
                    __builtin_bit_cast(half8, u), qf[c], acc, 0, 0, 0);
            }
            st[kt] = acc;
        }

        float mt = -INFINITY;
        #pragma unroll
        for (int kt = 0; kt < 4; ++kt)
            #pragma unroll
            for (int r = 0; r < 4; ++r) mt = fmaxf(mt, st[kt][r]);
        mt = fmaxf(mt, __shfl_xor(mt, 16));
        mt = fmaxf(mt, __shfl_xor(mt, 32));
        const float mnew = fmaxf(m_i, mt);
        const float sc = __expf(m_i - mnew);
        float rs = 0.f;
        #pragma unroll
        for (int kt = 0; kt < 4; ++kt)
            #pragma unroll
            for (int r = 0; r < 4; ++r) {
                const float p = __expf(st[kt][r] - mnew);
                st[kt][r] = p; rs += p;
            }
        rs += __shfl_xor(rs, 16);
        rs += __shfl_xor(rs, 32);
        l_i = l_i * sc + rs;
        m_i = mnew;

        #pragma unroll
        for (int kt = 0; kt < 4; ++kt) {
            union { _Float16 hh[4]; uint2 u; } pk;
            pk.hh[0] = (_Float16)st[kt][0]; pk.hh[1] = (_Float16)st[kt][1];
            pk.hh[2] = (_Float16)st[kt][2]; pk.hh[3] = (_Float16)st[kt][3];
            const int byte = w * 2048 + ql * 128 + kt * 32 + g * 8;
            *(uint2*)(PsB + (byte ^ ((ql & 7) << 4))) = pk.u;
        }

        const float f0 = __shfl(sc, g * 4 + 0);
        const float f1 = __shfl(sc, g * 4 + 1);
        const float f2 = __shfl(sc, g * 4 + 2);
        const float f3 = __shfl(sc, g * 4 + 3);
        #pragma unroll
        for (int vt = 0; vt < 8; ++vt) {
            o[vt][0] *= f0; o[vt][1] *= f1; o[vt][2] *= f2; o[vt][3] *= f3;
        }

        half8 pf[2];
        #pragma unroll
        for (int ks = 0; ks < 2; ++ks) {
            const int byte = w * 2048 + ql * 128 + ks * 64 + g * 16;
            uint4 u = *(const uint4*)(PsB + (byte ^ ((ql & 7) << 4)));
            pf[ks] = __builtin_bit_cast(half8, u);
        }
        #pragma unroll
        for (int vt = 0; vt < 8; ++vt) {
            const int v = vt * 16 + ql;
            uint4 u0 = *(const uint4*)(
                VsB + ((v * 128 + g * 16) ^ ((v & 7) << 4)));
            uint4 u1 = *(const uint4*)(
                VsB + ((v * 128 + 64 + g * 16) ^ ((v & 7) << 4)));
            o[vt] = __builtin_amdgcn_mfma_f32_16x16x32_f16(
                pf[0], __builtin_bit_cast(half8, u0), o[vt], 0, 0, 0);
            o[vt] = __builtin_amdgcn_mfma_f32_16x16x32_f16(
                pf[1], __builtin_bit_cast(half8, u1), o[vt], 0, 0, 0);
        }
    }

    const float invl = 1.f / l_i;
    const float fi0 = __shfl(invl, g * 4 + 0);
    const float fi1 = __shfl(invl, g * 4 + 1);
    const float fi2 = __shfl(invl, g * 4 + 2);
    const float fi3 = __shfl(invl, g * 4 + 3);
    #pragma unroll
    for (int vt = 0; vt < 8; ++vt) {
        const int v = vt * 16 + ql;
        _Float16* basep = (vt < 4) ? ax : ay;
        const int vv = v & 63;
        const float fi[4] = {fi0, fi1, fi2, fi3};
        #pragma unroll
        for (int r = 0; r < 4; ++r) {
            const int q = q0 + w * 16 + g * 4 + r;
            basep[((size_t)(b * SEQ + q)) * EDIM + h * HDIM + vv] =
                (_Float16)(o[vt][r] * fi[r]);
        }
    }
}

// ---------------------------------------------------------------------------
extern "C" void kernel_launch(void* const* d_in, const int* in_sizes, int n_in,
                              void* d_out, int out_size, void* d_ws, size_t ws_size,
                              hipStream_t stream)
{
    const float* act[6];
    for (int i = 0; i < 6; ++i) act[i] = (const float*)d_in[i];   // qx qy kx ky vx vy
    const float* W[8]; const float* Bv[8];
    for (int i = 0; i < 8; ++i) {                                  // Wqx Wqy Wkx Wky Wvx Wvy Wox Woy
        W[i]  = (const float*)d_in[6 + 2 * i];
        Bv[i] = (const float*)d_in[7 + 2 * i];
    }

    float* outx = (float*)d_out;              // [2,2048,512] fp32
    float* outy = outx + 2097152;

    _Float16* ws = (_Float16*)d_ws;
    _Float16* act16[6];
    for (int i = 0; i < 6; ++i) act16[i] = ws + (size_t)i * 2097152;
    _Float16* w16[8];
    for (int i = 0; i < 8; ++i) w16[i] = ws + 12582912 + (size_t)i * 262144;
    _Float16* Qt16 = ws + 14680064;           // [16][2048][192]
    _Float16* Kt16 = Qt16 + 6291456;
    _Float16* Vt16 = Kt16 + 6291456;          // [16][128][2048]
    _Float16* ax16 = Vt16 + 4194304;          // [B,S,E]
    _Float16* ay16 = ax16 + 2097152;          // total 35.65M halves = 68 MB

    // ---- cvt fp32 -> fp16
    Cvt8 ja{}, jw{};
    for (int i = 0; i < 6; ++i) { ja.s[i] = act[i]; ja.d[i] = act16[i]; }
    for (int i = 0; i < 8; ++i) { jw.s[i] = W[i];   jw.d[i] = w16[i];   }
    hipLaunchKernelGGL(cvt_fp16, dim3(512, 6), dim3(256), 0, stream, ja, 262144);
    hipLaunchKernelGGL(cvt_fp16, dim3(128, 8), dim3(256), 0, stream, jw, 32768);

    // ---- fused QKV projections
    PairArgs qa{act16[0], act16[1], w16[0], w16[1], Bv[0], Bv[1], Qt16, nullptr};
    PairArgs ka{act16[2], act16[3], w16[2], w16[3], Bv[2], Bv[3], Kt16, nullptr};
    PairArgs va{act16[4], act16[5], w16[4], w16[5], Bv[4], Bv[5], Vt16, nullptr};
    hipLaunchKernelGGL((gemm16<1>), dim3(8, 32, 3), dim3(256), 0, stream, qa, ka, va);

    // ---- attention
    hipLaunchKernelGGL(attn_mfma, dim3(SEQ / 128, 16), dim3(512), 0, stream,
                       Qt16, Kt16, Vt16, ax16, ay16);

    // ---- output projections
    PairArgs oa{ax16, ay16, w16[6], w16[7], Bv[6], Bv[7], outx, outy};
    hipLaunchKernelGGL((gemm16<0>), dim3(8, 32, 1), dim3(256), 0, stream, oa, oa, oa);
}